// Round 8
// baseline (165.915 us; speedup 1.0000x reference)
//
#include <hip/hip_runtime.h>
#include <stdint.h>

#define N_ROWS 4096
#define N_DIM  2048
#define MARGIN 0.3f
#define FLTMAX 3.402823466e+38f

// Tiling: 64 (A-rows) x 128 (B-cols) tiles. bi in [0,64), bj in [0,32),
// keep tiles with bj >= bi/2 (covers all upper-triangle cells) -> 1056 blocks
// (4.125/CU, balanced).
#define NBI 64
#define NBJ 32
#define NBLOCKS 1056         // sum_{bi=0}^{63} (32 - bi/2)

typedef __attribute__((ext_vector_type(8))) short short8;
typedef __attribute__((ext_vector_type(4))) float floatx4;

// Packed layout ("fragment order"): for 16-row group g (256 total) and k-chunk
// c (32 k each, 64 total), a 1 KB block at shorts-offset (g*64+c)*512. Lane l's
// 16 B fragment at l*8 shorts = row g*16+(l&15), k c*32+(l>>4)*8.. (verified
// absmax 0.0 through R7).

__device__ inline unsigned short f2bf_rne(float f) {
  unsigned u = __float_as_uint(f);
  unsigned r = 0x7fffu + ((u >> 16) & 1u);
  return (unsigned short)((u + r) >> 16);
}
__device__ inline float bf2f(unsigned short h) {
  return __uint_as_float(((unsigned)h) << 16);
}

// Async global->LDS DMA, 16 B per lane. LDS dest = firstlane base + lane*16.
// (Used by prep_kernel only.)
__device__ inline void gld_lds16(const void* g, void* l) {
  __builtin_amdgcn_global_load_lds(
      (const __attribute__((address_space(1))) void*)g,
      (__attribute__((address_space(3))) void*)l, 16, 0, 0);
}

// Counted vmcnt wait (even N, 0..30). Compile-time constant callers only.
// (prep_kernel's single-wave DMA chase.)
__device__ inline void wait_vmcnt_even(int n) {
  switch (n) {
    case 0:  asm volatile("s_waitcnt vmcnt(0)" ::: "memory"); break;
    case 2:  asm volatile("s_waitcnt vmcnt(2)" ::: "memory"); break;
    case 4:  asm volatile("s_waitcnt vmcnt(4)" ::: "memory"); break;
    case 6:  asm volatile("s_waitcnt vmcnt(6)" ::: "memory"); break;
    case 8:  asm volatile("s_waitcnt vmcnt(8)" ::: "memory"); break;
    case 10: asm volatile("s_waitcnt vmcnt(10)" ::: "memory"); break;
    case 12: asm volatile("s_waitcnt vmcnt(12)" ::: "memory"); break;
    case 14: asm volatile("s_waitcnt vmcnt(14)" ::: "memory"); break;
    case 16: asm volatile("s_waitcnt vmcnt(16)" ::: "memory"); break;
    case 18: asm volatile("s_waitcnt vmcnt(18)" ::: "memory"); break;
    case 20: asm volatile("s_waitcnt vmcnt(20)" ::: "memory"); break;
    case 22: asm volatile("s_waitcnt vmcnt(22)" ::: "memory"); break;
    case 24: asm volatile("s_waitcnt vmcnt(24)" ::: "memory"); break;
    case 26: asm volatile("s_waitcnt vmcnt(26)" ::: "memory"); break;
    case 28: asm volatile("s_waitcnt vmcnt(28)" ::: "memory"); break;
    default: asm volatile("s_waitcnt vmcnt(30)" ::: "memory"); break;
  }
}

// ---------------------------------------------------------------------------
// Kernel 1 (UNCHANGED from R4): cast fp32 -> bf16 AND repack into fragment
// order via LDS-DMA streaming; sq from the ROUNDED values (bit-identical
// chain). Counted vmcnt chase of the 32-deep DMA queue.
// ---------------------------------------------------------------------------
__global__ __launch_bounds__(256) void prep_kernel(
    const float* __restrict__ X, unsigned short* __restrict__ Xp,
    float* __restrict__ sq, unsigned* __restrict__ ap, unsigned* __restrict__ an)
{
  __shared__ __align__(16) float chunkf[16][2048];   // 16 x 8 KB = 128 KB
  const int b = blockIdx.x;
  const int t = threadIdx.x;
  const int r = t & 15, j = (t >> 4) & 3, w = t >> 6;

  const char* Xb = (const char*)(X + (size_t)b * 16 * N_DIM);
#pragma unroll
  for (int s = 0; s < 16; ++s) {
#pragma unroll
    for (int q = 0; q < 2; ++q) {
      const unsigned v = q * 256 + t;
      const unsigned rr = v >> 5, slot = v & 31, u = slot ^ (rr & 7);
      gld_lds16(Xb + (size_t)rr * 8192 + s * 512 + u * 16, &chunkf[s][v * 4]);
    }
  }
  __builtin_amdgcn_sched_barrier(0);   // pin all 32 DMA issues above the waits

  unsigned short* Op = Xp + (size_t)b * 64 * 512 + (size_t)(j * 16 + r) * 8;
  const unsigned u0 = (unsigned)(w * 8 + j * 2);
  const unsigned sl0 = (r * 32 + (u0 ^ (r & 7))) * 4;        // float index
  const unsigned sl1 = (r * 32 + ((u0 + 1) ^ (r & 7))) * 4;

  float acc = 0.f;
#pragma unroll
  for (int s = 0; s < 16; ++s) {
    wait_vmcnt_even(30 - 2 * s);       // chunk s's 2 ops retired (in-order)
    __builtin_amdgcn_sched_barrier(0);
    const int c = w + s * 4;
    float4 v0 = *(const float4*)&chunkf[s][sl0];
    float4 v1 = *(const float4*)&chunkf[s][sl1];
    short8 o;
    o[0] = (short)f2bf_rne(v0.x); o[1] = (short)f2bf_rne(v0.y);
    o[2] = (short)f2bf_rne(v0.z); o[3] = (short)f2bf_rne(v0.w);
    o[4] = (short)f2bf_rne(v1.x); o[5] = (short)f2bf_rne(v1.y);
    o[6] = (short)f2bf_rne(v1.z); o[7] = (short)f2bf_rne(v1.w);
#pragma unroll
    for (int e = 0; e < 8; ++e) {
      float f = bf2f((unsigned short)o[e]);
      acc = fmaf(f, f, acc);
    }
    *(short8*)(Op + (size_t)c * 512) = o;
  }
  acc += __shfl_xor(acc, 16, 64);
  acc += __shfl_xor(acc, 32, 64);
  __shared__ float part[4][16];
  if ((t & 63) < 16) part[w][r] = acc;
  __syncthreads();
  if (t < 16) {
    float s4 = part[0][t] + part[1][t] + part[2][t] + part[3][t];
    sq[b * 16 + t] = s4;
    ap[b * 16 + t] = 0u;           // max identity (dist >= 0)
    an[b * 16 + t] = 0x7f7fffffu;  // FLT_MAX bits
  }
}

// ---------------------------------------------------------------------------
// Kernel 2, R8: ZERO-LDS, ZERO-BARRIER streaming GEMM. The ~62 µs floor
// survived every sync-structure variant (R0-R7), so the barrier itself goes.
// 64x128 tile, 1x4 wave grid (wave w: all 64 rows x cols [w*32,w*32+32)).
// Both A (4 frags/chunk) and B (2 frags/chunk) stream global->register with
// a one-chunk ping-pong prefetch; the packed layout makes every load one
// coalesced 1 KB wave-read. A's 4x intra-block reuse is served by L1
// (8 KB/chunk working set). No __shared__, no __syncthreads -> waves only
// ever wait on their own loads; 16 waves/CU hide L2 latency. sq/lab read
// direct from global in the epilogue. Chunk order c=0..63 ascending with
// the same per-(mi,ni) MFMA chain as R3/R6 -> bit-identical acc.
// ---------------------------------------------------------------------------
__global__ __launch_bounds__(256, 4) void dist_kernel(
    const unsigned short* __restrict__ Xp, const float* __restrict__ sq,
    const int* __restrict__ lab, unsigned* __restrict__ ap, unsigned* __restrict__ an)
{
  // decode linear block id -> (bi, bj) with bj >= bi/2
  int p = blockIdx.x;
  int bi = 0;
  while (p >= NBJ - (bi >> 1)) { p -= NBJ - (bi >> 1); ++bi; }
  const int bj = (bi >> 1) + p;

  const int t = threadIdx.x;
  const int lane = t & 63;
  const int w = __builtin_amdgcn_readfirstlane(t >> 6);  // wave-uniform -> SGPR

  // Wave-uniform fragment base pointers (compiler: SGPR base + VGPR offset).
  // A group mi: shorts offset ((bi*4+mi)*64)*512; B group ni: ((bj*8+w*2+ni)*64)*512.
  const unsigned short* Ab[4];
  const unsigned short* Bp[2];
#pragma unroll
  for (int mi = 0; mi < 4; ++mi)
    Ab[mi] = Xp + ((size_t)(unsigned)(bi * 4 + mi) * 64) * 512;
#pragma unroll
  for (int ni = 0; ni < 2; ++ni)
    Bp[ni] = Xp + ((size_t)(unsigned)(bj * 8 + w * 2 + ni) * 64) * 512;

  const unsigned lo8 = (unsigned)lane * 8;   // per-lane 16 B fragment

#define LOADA(DST, C)                                                        \
  do {                                                                       \
    _Pragma("unroll")                                                        \
    for (int mi = 0; mi < 4; ++mi)                                           \
      DST[mi] = *(const short8*)(Ab[mi] + (unsigned)(C) * 512u + lo8);       \
  } while (0)
#define LOADB(DST, C)                                                        \
  do {                                                                       \
    _Pragma("unroll")                                                        \
    for (int ni = 0; ni < 2; ++ni)                                           \
      DST[ni] = *(const short8*)(Bp[ni] + (unsigned)(C) * 512u + lo8);       \
  } while (0)
#define MM(AF, BF)                                                           \
  do {                                                                       \
    _Pragma("unroll")                                                        \
    for (int mi = 0; mi < 4; ++mi)                                           \
      _Pragma("unroll")                                                      \
      for (int ni = 0; ni < 2; ++ni)                                         \
        acc[mi][ni] = __builtin_amdgcn_mfma_f32_16x16x32_bf16(               \
            AF[mi], BF[ni], acc[mi][ni], 0, 0, 0);                           \
  } while (0)

  floatx4 acc[4][2] = {};
  short8 aE[4], bE[2], aO[4], bO[2];     // even/odd chunk ping-pong sets

  LOADA(aE, 0); LOADB(bE, 0);
  LOADA(aO, 1); LOADB(bO, 1);

  for (int c = 0; c < 64; c += 2) {
    MM(aE, bE);                          // chunk c (regs read at MFMA issue)
    if (c + 2 < 64) { LOADA(aE, c + 2); LOADB(bE, c + 2); }  // prefetch even
    MM(aO, bO);                          // chunk c+1
    if (c + 3 < 64) { LOADA(aO, c + 3); LOADB(bO, c + 3); }  // prefetch odd
  }
#undef LOADA
#undef LOADB
#undef MM

  // Epilogue. C/D layout (m89): col = lane&15, row = (lane>>4)*4 + reg.
  // sq/lab read DIRECT from global (no LDS): tiny, L1/L2-served.
  const int cn = lane & 15, lg = lane >> 4;
  float sqc[2]; int labc[2];
#pragma unroll
  for (int ni = 0; ni < 2; ++ni) {
    int c = bj * 128 + w * 32 + ni * 16 + cn;
    sqc[ni] = sq[c]; labc[ni] = lab[c];
  }
  float cap[2] = {0.f, 0.f};
  float can[2] = {FLTMAX, FLTMAX};
#pragma unroll
  for (int mi = 0; mi < 4; ++mi) {
#pragma unroll
    for (int r = 0; r < 4; ++r) {
      const int rl = mi * 16 + lg * 4 + r;   // row within 64-tile
      const int R = bi * 64 + rl;
      const float si = sq[R];
      const int li = lab[R];
      float apv = 0.0f;
      float anv = FLTMAX;
#pragma unroll
      for (int ni = 0; ni < 2; ++ni) {
        float g = acc[mi][ni][r];
        float d2 = fmaf(-2.0f, g, si + sqc[ni]);
        d2 = fmaxf(d2, 1e-12f);
        float d = __builtin_amdgcn_sqrtf(d2);
        const bool same = (li == labc[ni]);
        const float dp = same ? d : 0.0f;
        const float dn = same ? FLTMAX : d;
        apv = fmaxf(apv, dp);
        anv = fminf(anv, dn);
        cap[ni] = fmaxf(cap[ni], dp);   // col-side (symmetric) partials
        can[ni] = fminf(can[ni], dn);
      }
      // row side: reduce over the 16 cn-lanes (same lg = same row)
#pragma unroll
      for (int m = 8; m >= 1; m >>= 1) {
        apv = fmaxf(apv, __shfl_xor(apv, m, 64));
        anv = fminf(anv, __shfl_xor(anv, m, 64));
      }
      if (cn == 0) {
        atomicMax(&ap[R], __float_as_uint(apv));
        atomicMin(&an[R], __float_as_uint(anv));
      }
    }
  }
  // col side: reduce over lg (xor 16,32) -> full 64 rows per column
#pragma unroll
  for (int ni = 0; ni < 2; ++ni) {
    float a = cap[ni], b = can[ni];
#pragma unroll
    for (int m = 16; m <= 32; m <<= 1) {
      a = fmaxf(a, __shfl_xor(a, m, 64));
      b = fminf(b, __shfl_xor(b, m, 64));
    }
    if (lg == 0) {
      int C = bj * 128 + w * 32 + ni * 16 + cn;
      atomicMax(&ap[C], __float_as_uint(a));
      atomicMin(&an[C], __float_as_uint(b));
    }
  }
}

// ---------------------------------------------------------------------------
// Kernel 3 (UNCHANGED from R4): loss = mean(relu(margin + dist_ap - dist_an))
// ---------------------------------------------------------------------------
__global__ __launch_bounds__(256) void finalize_kernel(
    const unsigned* __restrict__ ap, const unsigned* __restrict__ an,
    float* __restrict__ out)
{
  const int t = threadIdx.x;
  float av[16], bv[16];
#pragma unroll
  for (int q = 0; q < 16; ++q) {
    av[q] = __uint_as_float(ap[t + q * 256]);
    bv[q] = __uint_as_float(an[t + q * 256]);
  }
  float s = 0.f;
#pragma unroll
  for (int q = 0; q < 16; ++q) s += fmaxf(MARGIN + av[q] - bv[q], 0.0f);
#pragma unroll
  for (int m = 32; m >= 1; m >>= 1) s += __shfl_down(s, m, 64);
  __shared__ float wsum[4];
  const int lane = t & 63, w = t >> 6;
  if (lane == 0) wsum[w] = s;
  __syncthreads();
  if (t == 0) out[0] = (wsum[0] + wsum[1] + wsum[2] + wsum[3]) * (1.0f / N_ROWS);
}

extern "C" void kernel_launch(void* const* d_in, const int* in_sizes, int n_in,
                              void* d_out, int out_size, void* d_ws, size_t ws_size,
                              hipStream_t stream) {
  const float* X = (const float*)d_in[0];
  const int* lab = (const int*)d_in[1];
  float* out = (float*)d_out;

  char* ws = (char*)d_ws;
  unsigned short* Xp = (unsigned short*)ws;                           // 16 MB packed
  float* sq  = (float*)(ws + (size_t)N_ROWS * N_DIM * 2);             // 16 KB
  unsigned* ap = (unsigned*)((char*)sq + N_ROWS * sizeof(float));     // 16 KB
  unsigned* an = (unsigned*)((char*)ap + N_ROWS * sizeof(unsigned));  // 16 KB

  prep_kernel<<<N_ROWS / 16, 256, 0, stream>>>(X, Xp, sq, ap, an);
  dist_kernel<<<NBLOCKS, 256, 0, stream>>>(Xp, sq, lab, ap, an);
  finalize_kernel<<<1, 256, 0, stream>>>(ap, an, out);
}

// Round 9
// 130.811 us; speedup vs baseline: 1.2684x; 1.2684x over previous
//
#include <hip/hip_runtime.h>
#include <stdint.h>

#define N_ROWS 4096
#define N_DIM  2048
#define MARGIN 0.3f
#define NITER  (N_DIM / 64)  // BK=64 -> 32 K-iterations
#define FLTMAX 3.402823466e+38f

// Tiling: 64 (A-rows) x 128 (B-cols) tiles. bi in [0,64), bj in [0,32),
// keep tiles with bi <= 2*bj+1 (covers all upper-triangle cells) -> 1056
// blocks. R9: blocks are assigned to XCDs (assuming round-robin dispatch,
// xcd = blockIdx % 8, per m157/m192) so that each XCD owns 4 bj values
// (pairs {2x,31-2x},{2x+1,30-2x}; 66 blocks/pair -> exactly 132/XCD). All
// ~128 resident blocks of an XCD then share 4 B-panels (2 MB, L2-resident)
// and reuse A-panels up to 4x -> L2-miss (Infinity-Cache-path) traffic
// drops ~7x. Decode is bijective, so correctness is independent of the
// actual dispatch mapping.
#define NBI 64
#define NBJ 32
#define NBLOCKS 1056         // 132 x 8

typedef __attribute__((ext_vector_type(8))) short short8;
typedef __attribute__((ext_vector_type(4))) float floatx4;

// Packed layout ("fragment order"): for 16-row group g (256 total) and k-chunk
// c (32 k each, 64 total), a 1 KB block at shorts-offset (g*64+c)*512. Lane l's
// 16 B fragment at l*8 shorts = row g*16+(l&15), k c*32+(l>>4)*8.. (verified
// absmax 0.0 through R8).

__device__ inline unsigned short f2bf_rne(float f) {
  unsigned u = __float_as_uint(f);
  unsigned r = 0x7fffu + ((u >> 16) & 1u);
  return (unsigned short)((u + r) >> 16);
}
__device__ inline float bf2f(unsigned short h) {
  return __uint_as_float(((unsigned)h) << 16);
}

// Async global->LDS DMA, 16 B per lane. LDS dest = firstlane base + lane*16.
__device__ inline void gld_lds16(const void* g, void* l) {
  __builtin_amdgcn_global_load_lds(
      (const __attribute__((address_space(1))) void*)g,
      (__attribute__((address_space(3))) void*)l, 16, 0, 0);
}

// Counted vmcnt wait (even N, 0..30). Compile-time constant callers only.
// (prep_kernel's single-wave DMA chase.)
__device__ inline void wait_vmcnt_even(int n) {
  switch (n) {
    case 0:  asm volatile("s_waitcnt vmcnt(0)" ::: "memory"); break;
    case 2:  asm volatile("s_waitcnt vmcnt(2)" ::: "memory"); break;
    case 4:  asm volatile("s_waitcnt vmcnt(4)" ::: "memory"); break;
    case 6:  asm volatile("s_waitcnt vmcnt(6)" ::: "memory"); break;
    case 8:  asm volatile("s_waitcnt vmcnt(8)" ::: "memory"); break;
    case 10: asm volatile("s_waitcnt vmcnt(10)" ::: "memory"); break;
    case 12: asm volatile("s_waitcnt vmcnt(12)" ::: "memory"); break;
    case 14: asm volatile("s_waitcnt vmcnt(14)" ::: "memory"); break;
    case 16: asm volatile("s_waitcnt vmcnt(16)" ::: "memory"); break;
    case 18: asm volatile("s_waitcnt vmcnt(18)" ::: "memory"); break;
    case 20: asm volatile("s_waitcnt vmcnt(20)" ::: "memory"); break;
    case 22: asm volatile("s_waitcnt vmcnt(22)" ::: "memory"); break;
    case 24: asm volatile("s_waitcnt vmcnt(24)" ::: "memory"); break;
    case 26: asm volatile("s_waitcnt vmcnt(26)" ::: "memory"); break;
    case 28: asm volatile("s_waitcnt vmcnt(28)" ::: "memory"); break;
    default: asm volatile("s_waitcnt vmcnt(30)" ::: "memory"); break;
  }
}

// ---------------------------------------------------------------------------
// Kernel 1 (UNCHANGED from R4): cast fp32 -> bf16 AND repack into fragment
// order via LDS-DMA streaming; sq from the ROUNDED values (bit-identical
// chain). Counted vmcnt chase of the 32-deep DMA queue.
// ---------------------------------------------------------------------------
__global__ __launch_bounds__(256) void prep_kernel(
    const float* __restrict__ X, unsigned short* __restrict__ Xp,
    float* __restrict__ sq, unsigned* __restrict__ ap, unsigned* __restrict__ an)
{
  __shared__ __align__(16) float chunkf[16][2048];   // 16 x 8 KB = 128 KB
  const int b = blockIdx.x;
  const int t = threadIdx.x;
  const int r = t & 15, j = (t >> 4) & 3, w = t >> 6;

  const char* Xb = (const char*)(X + (size_t)b * 16 * N_DIM);
#pragma unroll
  for (int s = 0; s < 16; ++s) {
#pragma unroll
    for (int q = 0; q < 2; ++q) {
      const unsigned v = q * 256 + t;
      const unsigned rr = v >> 5, slot = v & 31, u = slot ^ (rr & 7);
      gld_lds16(Xb + (size_t)rr * 8192 + s * 512 + u * 16, &chunkf[s][v * 4]);
    }
  }
  __builtin_amdgcn_sched_barrier(0);   // pin all 32 DMA issues above the waits

  unsigned short* Op = Xp + (size_t)b * 64 * 512 + (size_t)(j * 16 + r) * 8;
  const unsigned u0 = (unsigned)(w * 8 + j * 2);
  const unsigned sl0 = (r * 32 + (u0 ^ (r & 7))) * 4;        // float index
  const unsigned sl1 = (r * 32 + ((u0 + 1) ^ (r & 7))) * 4;

  float acc = 0.f;
#pragma unroll
  for (int s = 0; s < 16; ++s) {
    wait_vmcnt_even(30 - 2 * s);       // chunk s's 2 ops retired (in-order)
    __builtin_amdgcn_sched_barrier(0);
    const int c = w + s * 4;
    float4 v0 = *(const float4*)&chunkf[s][sl0];
    float4 v1 = *(const float4*)&chunkf[s][sl1];
    short8 o;
    o[0] = (short)f2bf_rne(v0.x); o[1] = (short)f2bf_rne(v0.y);
    o[2] = (short)f2bf_rne(v0.z); o[3] = (short)f2bf_rne(v0.w);
    o[4] = (short)f2bf_rne(v1.x); o[5] = (short)f2bf_rne(v1.y);
    o[6] = (short)f2bf_rne(v1.z); o[7] = (short)f2bf_rne(v1.w);
#pragma unroll
    for (int e = 0; e < 8; ++e) {
      float f = bf2f((unsigned short)o[e]);
      acc = fmaf(f, f, acc);
    }
    *(short8*)(Op + (size_t)c * 512) = o;
  }
  acc += __shfl_xor(acc, 16, 64);
  acc += __shfl_xor(acc, 32, 64);
  __shared__ float part[4][16];
  if ((t & 63) < 16) part[w][r] = acc;
  __syncthreads();
  if (t < 16) {
    float s4 = part[0][t] + part[1][t] + part[2][t] + part[3][t];
    sq[b * 16 + t] = s4;
    ap[b * 16 + t] = 0u;           // max identity (dist >= 0)
    an[b * 16 + t] = 0x7f7fffffu;  // FLT_MAX bits
  }
}

// ---------------------------------------------------------------------------
// Kernel 2, R9: EXACTLY the R3 kernel (best measured: 62.4 us, absmax 0.0)
// -- 64x128 tile, 1x4 wave grid, acc[4][2], A staged in LDS via gld_lds
// (double-buffered, one barrier/iter), B direct global->register prefetch --
// with ONLY the blockid->(bi,bj) decode changed to the XCD-paired-bj map.
// ---------------------------------------------------------------------------
__global__ __launch_bounds__(256, 4) void dist_kernel(
    const unsigned short* __restrict__ Xp, const float* __restrict__ sq,
    const int* __restrict__ lab, unsigned* __restrict__ ap, unsigned* __restrict__ an)
{
  __shared__ __align__(16) unsigned short As[2][4096];   // 2 x 8 KB (64 rows x 64 k)
  __shared__ float sqi[64], sqj[128];
  __shared__ int labi[64], labj[128];

  // R9 decode: x = target XCD (round-robin assumption), r = slot in [0,132).
  // XCD x owns bj in {2x, 31-2x, 2x+1, 30-2x}; within each bj, bi ascends
  // over its full legal range [0, 2bj+1]. Bijective onto the 1056 tiles.
  int bi, bj;
  {
    const int x = (int)(blockIdx.x & 7);
    int r = (int)(blockIdx.x >> 3);
    const int c0 = 4 * x + 2;            // bj = 2x      (bi <= 4x+1)
    const int c1 = 64 - 4 * x;           // bj = 31-2x   (bi <= 63-4x)
    const int c2 = 4 * x + 4;            // bj = 2x+1    (bi <= 4x+3)
    if (r < c0)                { bj = 2 * x;      bi = r; }
    else if (r < c0 + c1)      { bj = 31 - 2 * x; bi = r - c0; }
    else if (r < c0 + c1 + c2) { bj = 2 * x + 1;  bi = r - c0 - c1; }
    else                       { bj = 30 - 2 * x; bi = r - c0 - c1 - c2; }
  }

  const int t = threadIdx.x;
  const int lane = t & 63, w = t >> 6;     // 4 waves, 1x4 grid: wave w owns
                                           // cols [w*32, w*32+32), all 64 rows

  if (t < 64)       { int rr = bi * 64 + t;         sqi[t] = sq[rr];        labi[t] = lab[rr]; }
  else if (t < 192) { int cc = bj * 128 + (t - 64); sqj[t - 64] = sq[cc];   labj[t - 64] = lab[cc]; }

  // A staging: identity chunk map, 512 x 16B units (2/thread). unit u: group
  // gg = u>>7 (wave-uniform), off = u&127 (lane-contiguous) -> legal gld_lds.
  unsigned gA[2], loA[2];
#pragma unroll
  for (int q = 0; q < 2; ++q) {
    const unsigned u = q * 256 + t;
    gA[q] = ((unsigned)(bi * 4 + (u >> 7)) * 64) * 512 + (u & 127) * 8;
    loA[q] = u * 8;
  }
  // B direct: wave w's col 16-groups are (w*2) and (w*2+1). Fragment for
  // (ni, it, kh) at Bb[ni] + it*1024 + kh*512 (shorts), per-lane 16 B.
  const unsigned short* Bb[2];
#pragma unroll
  for (int ni = 0; ni < 2; ++ni)
    Bb[ni] = Xp + ((size_t)(unsigned)(bj * 8 + w * 2 + ni) * 64) * 512 + (unsigned)lane * 8;

#define STAGE_A(BUF, IT)                                                     \
  do {                                                                       \
    _Pragma("unroll")                                                        \
    for (int q = 0; q < 2; ++q)                                              \
      gld_lds16(Xp + gA[q] + (unsigned)(IT) * 1024u, &As[BUF][loA[q]]);      \
  } while (0)

  short8 bc[2][2], bn[2][2];
  STAGE_A(0, 0);
#pragma unroll
  for (int ni = 0; ni < 2; ++ni)
#pragma unroll
    for (int kh = 0; kh < 2; ++kh)
      bc[ni][kh] = *(const short8*)(Bb[ni] + kh * 512);
  __syncthreads();                         // A(0) drained + sqi/sqj visible

  floatx4 acc[4][2] = {};

  for (int it = 0; it < NITER; ++it) {
    const int cur = it & 1;
    const bool has_next = (it + 1 < NITER);
    if (has_next) {
      STAGE_A(cur ^ 1, it + 1);            // async DMA into other buffer
#pragma unroll
      for (int ni = 0; ni < 2; ++ni)
#pragma unroll
        for (int kh = 0; kh < 2; ++kh)
          bn[ni][kh] = *(const short8*)(Bb[ni] + (unsigned)(it + 1) * 1024u + kh * 512);
    }

#pragma unroll
    for (int kh = 0; kh < 2; ++kh) {
      short8 af[4];
#pragma unroll
      for (int mi = 0; mi < 4; ++mi)
        af[mi] = *(const short8*)&As[cur][(mi * 2 + kh) * 512 + lane * 8];
#pragma unroll
      for (int mi = 0; mi < 4; ++mi)
#pragma unroll
        for (int ni = 0; ni < 2; ++ni)
          acc[mi][ni] = __builtin_amdgcn_mfma_f32_16x16x32_bf16(
              af[mi], bc[ni][kh], acc[mi][ni], 0, 0, 0);
    }

    // ONE barrier per iter: all waves' As[cur] reads done (safe to overwrite
    // next iter) AND the implicit vmcnt(0) drains the DMA into As[cur^1].
    __syncthreads();
    if (has_next) {
#pragma unroll
      for (int ni = 0; ni < 2; ++ni)
#pragma unroll
        for (int kh = 0; kh < 2; ++kh)
          bc[ni][kh] = bn[ni][kh];
    }
  }
#undef STAGE_A

  // Epilogue. C/D layout (m89): col = lane&15, row = (lane>>4)*4 + reg.
  const int cn = lane & 15, lg = lane >> 4;
  float sqc[2]; int labc[2];
#pragma unroll
  for (int ni = 0; ni < 2; ++ni) {
    int c = w * 32 + ni * 16 + cn;
    sqc[ni] = sqj[c]; labc[ni] = labj[c];
  }
  float cap[2] = {0.f, 0.f};
  float can[2] = {FLTMAX, FLTMAX};
#pragma unroll
  for (int mi = 0; mi < 4; ++mi) {
#pragma unroll
    for (int r = 0; r < 4; ++r) {
      const int rl = mi * 16 + lg * 4 + r;   // row within 64-tile
      const float si = sqi[rl];
      const int li = labi[rl];
      float apv = 0.0f;
      float anv = FLTMAX;
#pragma unroll
      for (int ni = 0; ni < 2; ++ni) {
        float g = acc[mi][ni][r];
        float d2 = fmaf(-2.0f, g, si + sqc[ni]);
        d2 = fmaxf(d2, 1e-12f);
        float d = __builtin_amdgcn_sqrtf(d2);
        const bool same = (li == labc[ni]);
        const float dp = same ? d : 0.0f;
        const float dn = same ? FLTMAX : d;
        apv = fmaxf(apv, dp);
        anv = fminf(anv, dn);
        cap[ni] = fmaxf(cap[ni], dp);   // col-side (symmetric) partials
        can[ni] = fminf(can[ni], dn);
      }
      // row side: reduce over the 16 cn-lanes (same lg = same row)
#pragma unroll
      for (int m = 8; m >= 1; m >>= 1) {
        apv = fmaxf(apv, __shfl_xor(apv, m, 64));
        anv = fminf(anv, __shfl_xor(anv, m, 64));
      }
      if (cn == 0) {
        int R = bi * 64 + rl;
        atomicMax(&ap[R], __float_as_uint(apv));
        atomicMin(&an[R], __float_as_uint(anv));
      }
    }
  }
  // col side: reduce over lg (xor 16,32) -> full 64 rows per column
#pragma unroll
  for (int ni = 0; ni < 2; ++ni) {
    float a = cap[ni], b = can[ni];
#pragma unroll
    for (int m = 16; m <= 32; m <<= 1) {
      a = fmaxf(a, __shfl_xor(a, m, 64));
      b = fminf(b, __shfl_xor(b, m, 64));
    }
    if (lg == 0) {
      int C = bj * 128 + w * 32 + ni * 16 + cn;
      atomicMax(&ap[C], __float_as_uint(a));
      atomicMin(&an[C], __float_as_uint(b));
    }
  }
}

// ---------------------------------------------------------------------------
// Kernel 3 (UNCHANGED from R4): loss = mean(relu(margin + dist_ap - dist_an))
// ---------------------------------------------------------------------------
__global__ __launch_bounds__(256) void finalize_kernel(
    const unsigned* __restrict__ ap, const unsigned* __restrict__ an,
    float* __restrict__ out)
{
  const int t = threadIdx.x;
  float av[16], bv[16];
#pragma unroll
  for (int q = 0; q < 16; ++q) {
    av[q] = __uint_as_float(ap[t + q * 256]);
    bv[q] = __uint_as_float(an[t + q * 256]);
  }
  float s = 0.f;
#pragma unroll
  for (int q = 0; q < 16; ++q) s += fmaxf(MARGIN + av[q] - bv[q], 0.0f);
#pragma unroll
  for (int m = 32; m >= 1; m >>= 1) s += __shfl_down(s, m, 64);
  __shared__ float wsum[4];
  const int lane = t & 63, w = t >> 6;
  if (lane == 0) wsum[w] = s;
  __syncthreads();
  if (t == 0) out[0] = (wsum[0] + wsum[1] + wsum[2] + wsum[3]) * (1.0f / N_ROWS);
}

extern "C" void kernel_launch(void* const* d_in, const int* in_sizes, int n_in,
                              void* d_out, int out_size, void* d_ws, size_t ws_size,
                              hipStream_t stream) {
  const float* X = (const float*)d_in[0];
  const int* lab = (const int*)d_in[1];
  float* out = (float*)d_out;

  char* ws = (char*)d_ws;
  unsigned short* Xp = (unsigned short*)ws;                           // 16 MB packed
  float* sq  = (float*)(ws + (size_t)N_ROWS * N_DIM * 2);             // 16 KB
  unsigned* ap = (unsigned*)((char*)sq + N_ROWS * sizeof(float));     // 16 KB
  unsigned* an = (unsigned*)((char*)ap + N_ROWS * sizeof(unsigned));  // 16 KB

  prep_kernel<<<N_ROWS / 16, 256, 0, stream>>>(X, Xp, sq, ap, an);
  dist_kernel<<<NBLOCKS, 256, 0, stream>>>(Xp, sq, lab, ap, an);
  finalize_kernel<<<1, 256, 0, stream>>>(ap, an, out);
}